// Round 17
// baseline (168.095 us; speedup 1.0000x reference)
//
#include <hip/hip_runtime.h>

typedef __attribute__((ext_vector_type(8))) short short8;
typedef __attribute__((ext_vector_type(4))) float f32x4;
typedef __attribute__((ext_vector_type(2))) unsigned int u32x2;
typedef __attribute__((ext_vector_type(4))) unsigned int u32x4;

#define MFMA16x32(A, B, C) \
  __builtin_amdgcn_mfma_f32_16x16x32_bf16((A), (B), (C), 0, 0, 0)

// Async global->LDS, 16B/lane. Global addr is per-lane; LDS dest is the
// WAVE-UNIFORM base (HW scatters lane i -> base + i*16).
__device__ __forceinline__ void async_cp16(const unsigned short* g, void* l) {
  __builtin_amdgcn_global_load_lds(
      (const __attribute__((address_space(1))) unsigned int*)g,
      (__attribute__((address_space(3))) unsigned int*)l, 16, 0, 0);
}

__device__ __forceinline__ unsigned int fbits(float f) {
  return __builtin_bit_cast(unsigned int, f);
}
// pack two floats -> two bf16 (truncate): low ushort = a, high = b
__device__ __forceinline__ unsigned int pack_bf16(float a, float b) {
  return __builtin_amdgcn_perm(fbits(b), fbits(a), 0x07060302u);
}
__device__ __forceinline__ unsigned short bf16_rne(float f) {
  unsigned int u = fbits(f);
  return (unsigned short)((u + 0x8000u) >> 16);
}
// relu on a PACKED bf16 pair: bf16 bit patterns are sign-monotone as i16, so
// max_i16 with 0 zeroes the negative half-words. 1 instr for 2 elements.
__device__ __forceinline__ unsigned int relu_pk_bf16(unsigned int x) {
  unsigned int r;
  asm("v_pk_max_i16 %0, %1, 0" : "=v"(r) : "v"(x));
  return r;
}

// ---------------------------------------------------------------------------
// Kernel 0 (fused): blocks < 4096: x fp32 -> bf16.  blocks >= 4096: W -> WT
// (bf16, [n][k]) for all three weights.
// ---------------------------------------------------------------------------
__global__ __launch_bounds__(256) void prep_kernel(
    const float* __restrict__ x, unsigned short* __restrict__ xb,
    const float* __restrict__ Wq, const float* __restrict__ Wk,
    const float* __restrict__ Wv, unsigned short* __restrict__ WT) {
  __shared__ float tile[32][33];
  if (blockIdx.x < 4096) {
    const size_t i = ((size_t)blockIdx.x * 256 + threadIdx.x) * 4;
    const float4 f = *(const float4*)(x + i);
    u32x2 u = {(unsigned int)bf16_rne(f.x) | ((unsigned int)bf16_rne(f.y) << 16),
               (unsigned int)bf16_rne(f.z) | ((unsigned int)bf16_rne(f.w) << 16)};
    *(u32x2*)(xb + i) = u;
    return;
  }
  const int bid = blockIdx.x - 4096;
  const int g = bid / 64, rem = bid % 64;
  const int k0 = (rem >> 3) * 32, n0 = (rem & 7) * 32;
  const float* W = (g == 0) ? Wq : (g == 1) ? Wk : Wv;
  const int t = threadIdx.x;
  {
    const int kr = t >> 3, nc = (t & 7) * 4;
    const float4 f = *(const float4*)(W + (size_t)(k0 + kr) * 256 + n0 + nc);
    tile[kr][nc + 0] = f.x; tile[kr][nc + 1] = f.y;
    tile[kr][nc + 2] = f.z; tile[kr][nc + 3] = f.w;
  }
  __syncthreads();
  {
    const int nr = t >> 3, kc = (t & 7) * 4;
    unsigned int u0 = (unsigned int)bf16_rne(tile[kc + 0][nr]) |
                      ((unsigned int)bf16_rne(tile[kc + 1][nr]) << 16);
    unsigned int u1 = (unsigned int)bf16_rne(tile[kc + 2][nr]) |
                      ((unsigned int)bf16_rne(tile[kc + 3][nr]) << 16);
    u32x2 u = {u0, u1};
    *(u32x2*)(WT + (size_t)g * 65536 + (size_t)(n0 + nr) * 256 + k0 + kc) = u;
  }
}

// ---------------------------------------------------------------------------
// Kernel 1: fused QKV projection GEMM, LDS-staged, BK=64 dbuf. 128m x 128n
// tile, 4 waves. Q/K written packed per head: QH/KH[bh][n][32] (Q pre-scaled
// by 1/sqrt(dk)); V written transposed VT[bh*32+d][n] with a key-order
// permutation inside each 32-n group: phys n = s*16+quad*4+r stored at
// n' = (n&~31)|(quad<<3)|(s<<2)|r, so attn's packed S^T registers ARE the
// K=32 MFMA B-fragment (reduction over keys is order-invariant as long as
// P and V use the same key order).
// ---------------------------------------------------------------------------
__global__ __launch_bounds__(256, 2) void proj_kernel(
    const unsigned short* __restrict__ xb, const unsigned short* __restrict__ WT,
    unsigned short* __restrict__ QH, unsigned short* __restrict__ KH,
    unsigned short* __restrict__ VT) {
  __shared__ __align__(16) char smem[65536];  // dbuf x (A 16K + B 16K)
  const int tid = threadIdx.x;
  const int w = tid >> 6, lane = tid & 63, l15 = lane & 15, quad = lane >> 4;
  const int bid = blockIdx.x;
  const int mtile = bid / 6, nt = bid % 6;
  const int g = nt >> 1, n0 = (nt & 1) * 128;
  const int m0 = mtile * 128;

  // Staging: wave w covers tile-rows w*32..+32 (4 instrs of 8 rows each).
  // LDS row r holds global 16B-seg (u ^ (r&7)) at seg u (XOR swizzle).
  const int srow = lane >> 3, useg = lane & 7;
  const int swz = (useg ^ srow) * 8;  // shorts
  const unsigned short* aS = xb + (size_t)(m0 + w * 32 + srow) * 256 + swz;
  const unsigned short* bS =
      WT + (size_t)g * 65536 + (size_t)(n0 + w * 32 + srow) * 256 + swz;

#pragma unroll
  for (int j = 0; j < 4; j++) {  // preload k-tile 0 -> buf 0
    async_cp16(aS + j * 2048, smem + w * 4096 + j * 1024);
    async_cp16(bS + j * 2048, smem + 16384 + w * 4096 + j * 1024);
  }
  __syncthreads();

  const f32x4 zero = {0.f, 0.f, 0.f, 0.f};
  f32x4 acc[2][8];
#pragma unroll
  for (int s = 0; s < 2; s++)
#pragma unroll
    for (int c = 0; c < 8; c++) acc[s][c] = zero;

  const int sw = l15 & 7;
  for (int t = 0; t < 4; t++) {
    const int nb = t & 1;
    const int kn = ((t + 1) & 3) * 64;  // wraps; last prefetch harmless
#pragma unroll
    for (int j = 0; j < 4; j++) {
      async_cp16(aS + kn + j * 2048,
                 smem + (nb ^ 1) * 32768 + w * 4096 + j * 1024);
      async_cp16(bS + kn + j * 2048,
                 smem + (nb ^ 1) * 32768 + 16384 + w * 4096 + j * 1024);
    }
    const char* Ab = smem + nb * 32768;
    const char* Bb = Ab + 16384;
#pragma unroll
    for (int ks = 0; ks < 2; ks++) {
      const int seg = ((ks * 4 + quad) ^ sw) * 16;
      short8 af[2], bf[8];
#pragma unroll
      for (int s = 0; s < 2; s++)
        af[s] = *(const short8*)(Ab + (w * 32 + s * 16 + l15) * 128 + seg);
#pragma unroll
      for (int c = 0; c < 8; c++)
        bf[c] = *(const short8*)(Bb + (c * 16 + l15) * 128 + seg);
      if (g < 2) {
#pragma unroll
        for (int s = 0; s < 2; s++)
#pragma unroll
          for (int c = 0; c < 8; c++)
            acc[s][c] = MFMA16x32(bf[c], af[s], acc[s][c]);  // swapped
      } else {
#pragma unroll
        for (int s = 0; s < 2; s++)
#pragma unroll
          for (int c = 0; c < 8; c++)
            acc[s][c] = MFMA16x32(af[s], bf[c], acc[s][c]);
      }
    }
    __syncthreads();
  }

  if (g < 2) {
    // Swapped orientation: rows m0+w*32+s*16+l15 (seq), cols n0+c*16+quad*4
    // (+reg) = feature -> packed 8B stores into [bh][n][32].
    unsigned short* O = g ? KH : QH;
    const float sc = g ? 1.0f : 0.17677669529663688f;  // 1/sqrt(32) into Q
#pragma unroll
    for (int s = 0; s < 2; s++)
#pragma unroll
      for (int c = 0; c < 8; c++) {
        const int row = m0 + w * 32 + s * 16 + l15;
        const int col = n0 + c * 16 + quad * 4;
        const int bb = row >> 12, nn = row & 4095;
        const int hh = col >> 5, dl = col & 31;
        u32x2 pk = {pack_bf16(acc[s][c][0] * sc, acc[s][c][1] * sc),
                    pack_bf16(acc[s][c][2] * sc, acc[s][c][3] * sc)};
        *(u32x2*)(O + ((size_t)(bb * 8 + hh) * 4096 + nn) * 32 + dl) = pk;
      }
  } else {
    // Natural orientation: reg-dim = 4 consecutive n -> contiguous in VT.
    // Key-permutation: phys n low5 = s*16+quad*4+r stored at quad*8+s*4+r.
#pragma unroll
    for (int s = 0; s < 2; s++)
#pragma unroll
      for (int c = 0; c < 8; c++) {
        const int col = n0 + c * 16 + l15;  // h*32 + d
        const int hh = col >> 5, dl = col & 31;
        const int row = m0 + w * 32 + s * 16 + quad * 4;
        const int bb = row >> 12;
        const int nn = (row & 4064) | (quad << 3) | ((s & 1) << 2);  // &~31
        u32x2 pk = {pack_bf16(acc[s][c][0], acc[s][c][1]),
                    pack_bf16(acc[s][c][2], acc[s][c][3])};
        *(u32x2*)(VT + (size_t)((bb * 8 + hh) * 32 + dl) * 4096 + nn) = pk;
      }
  }
}

// ---------------------------------------------------------------------------
// Kernel 1.5: partial M = K^T V. Grid 256 = 32 bh x 8 key-slices (R16's
// 32-block version left 224 CUs idle and its 256-scalar-load gather chain
// cost ~13us; now each block handles 512 keys: 8x coverage, 32 gather loads
// per lane). Per block: wave w covers keys slice*512 + w*64 (+2 groups of
// 32). A = V^T frag (16B contiguous from VT, keys in VT order); B = K frag
// by register element-inserts with constant indices (no scratch). VT-pos
// p=quad*8+j decodes to key kb+(j>>2)*16+quad*4+(j&3) — same key pairing
// for A and B -> order-invariant sum. LDS reduce across 8 waves; wave 0
// writes the f32 partial in attn's per-lane A-frag order:
// MP[blk*1024 + dt*512 + lane*8 + j]. attn sums the 8 slices per bh inline.
// ---------------------------------------------------------------------------
__global__ __launch_bounds__(512) void mkv_kernel(
    const unsigned short* __restrict__ KH, const unsigned short* __restrict__ VT,
    float* __restrict__ MP) {
  __shared__ __align__(16) float Mred[8][32][32];  // 32KB
  const int tid = threadIdx.x;
  const int w = tid >> 6, lane = tid & 63, l15 = lane & 15, quad = lane >> 4;
  const int blk = blockIdx.x;
  const int bh = blk >> 3, slice = blk & 7;

  const f32x4 zero = {0.f, 0.f, 0.f, 0.f};
  f32x4 mm[2][2];
#pragma unroll
  for (int dt = 0; dt < 2; dt++)
#pragma unroll
    for (int it = 0; it < 2; it++) mm[dt][it] = zero;

  const unsigned short* Vg = VT + ((size_t)bh * 32 + l15) * 4096 + quad * 8;
  const unsigned short* Kg = KH + (size_t)bh * 4096 * 32;

#pragma unroll
  for (int g = 0; g < 2; g++) {
    const int kb = slice * 512 + w * 64 + g * 32;
    short8 va[2];
#pragma unroll
    for (int dt = 0; dt < 2; dt++)
      va[dt] = *(const short8*)(Vg + (size_t)dt * 16 * 4096 + kb);
    short8 kv0, kv1;
#pragma unroll
    for (int j = 0; j < 8; j++) {  // VT-pos p=quad*8+j -> natural key n(p)
      const int key = kb + ((j >> 2) << 4) + quad * 4 + (j & 3);
      const size_t base = (size_t)key * 32 + l15;
      kv0[j] = (short)Kg[base];
      kv1[j] = (short)Kg[base + 16];
    }
#pragma unroll
    for (int dt = 0; dt < 2; dt++) {
      mm[dt][0] = MFMA16x32(va[dt], kv0, mm[dt][0]);
      mm[dt][1] = MFMA16x32(va[dt], kv1, mm[dt][1]);
    }
  }
  // D layout: row d_local = quad*4+r (+dt*16), col i_local = l15 (+it*16).
#pragma unroll
  for (int dt = 0; dt < 2; dt++)
#pragma unroll
    for (int it = 0; it < 2; it++)
#pragma unroll
      for (int r = 0; r < 4; r++)
        Mred[w][dt * 16 + quad * 4 + r][it * 16 + l15] = mm[dt][it][r];
  __syncthreads();

  if (w == 0) {
#pragma unroll
    for (int dt = 0; dt < 2; dt++) {
      f32x4 sa = zero, sb = zero;
#pragma unroll
      for (int ww = 0; ww < 8; ww++) {
        const float* p = &Mred[ww][dt * 16 + l15][quad * 8];
        sa += *(const f32x4*)p;
        sb += *(const f32x4*)(p + 4);
      }
      float* o = MP + (size_t)blk * 1024 + dt * 512 + lane * 8;
      *(f32x4*)o = sa;
      *(f32x4*)(o + 4) = sb;
    }
  }
}

// ---------------------------------------------------------------------------
// Kernel 2: attention = R4/R14-verified structure + leaky decomposition
// (R16: attn 63.8us, MfmaUtil 45, VALUBusy 41.6): leaky(x) = 0.8*relu(x) +
// 0.2*x  =>  O = 0.8 * V^T relu(S) + 0.2 * Qs*M, M = K^T V from mkv_kernel
// partials (8 f32 slices summed inline here — 32 L2-hit f32x4 loads, once
// per block). Main-loop leaky: pack + v_pk_max_i16 (4 instrs/tile).
// Epilogue: out = 0.8*acc + 0.2*mfma(ma[dt], qf[s]) — ma is the A-frag
// [d=l15][i=quad*8+j], qf doubles as the B-frag [k=i][n=q=l15].
// Dead ends (do not revisit): split-K (101), counted-vmcnt (97), 2-tile
// epochs (92), q_w=16 (110), q_w=64 (97), 4-wave domains (101), setprio
// (104), LDS-free (191), leaky_pack f32x2 helper (98), in-attn M (104),
// 32-block mkv (13us).
// ---------------------------------------------------------------------------
__global__ __launch_bounds__(512, 4) void attn_kernel(
    const unsigned short* __restrict__ QH, const unsigned short* __restrict__ KH,
    const unsigned short* __restrict__ VT, const float* __restrict__ MP,
    float* __restrict__ out) {
  __shared__ __align__(16) char smem[16384];  // dbuf x (K 4K + V 4K)
  const int tid = threadIdx.x;
  const int w = tid >> 6, lane = tid & 63, l15 = lane & 15, quad = lane >> 4;
  const int bid = blockIdx.x;
  const int bh = bid & 31, qh = bid >> 5;  // bid%8 = bh%8: KV L2-local per XCD
  const int b = bh >> 3, h = bh & 7;
  const int qbase = qh * 256 + w * 32;

  // Q frags once (packed head layout -> contiguous loads).
  const unsigned short* Qp =
      QH + ((size_t)bh * 4096 + qbase + l15) * 32 + quad * 8;
  short8 qf[2];
#pragma unroll
  for (int s = 0; s < 2; s++) qf[s] = *(const short8*)(Qp + (size_t)s * 512);

  const f32x4 zero = {0.f, 0.f, 0.f, 0.f};

  // M frags: sum the 8 f32 partial slices, pack to bf16 A-frag order.
  short8 ma[2];
  {
    f32x4 macc[2][2];
#pragma unroll
    for (int dt = 0; dt < 2; dt++) {
      macc[dt][0] = zero;
      macc[dt][1] = zero;
    }
#pragma unroll
    for (int sl = 0; sl < 8; sl++) {
      const float* p = MP + (size_t)(bh * 8 + sl) * 1024 + lane * 8;
#pragma unroll
      for (int dt = 0; dt < 2; dt++) {
        macc[dt][0] += *(const f32x4*)(p + dt * 512);
        macc[dt][1] += *(const f32x4*)(p + dt * 512 + 4);
      }
    }
#pragma unroll
    for (int dt = 0; dt < 2; dt++) {
      u32x4 mw = {pack_bf16(macc[dt][0][0], macc[dt][0][1]),
                  pack_bf16(macc[dt][0][2], macc[dt][0][3]),
                  pack_bf16(macc[dt][1][0], macc[dt][1][1]),
                  pack_bf16(macc[dt][1][2], macc[dt][1][3])};
      ma[dt] = __builtin_bit_cast(short8, mw);
    }
  }

  // Staging setup (per lane global src; wave-uniform LDS base).
  const bool isK = (w < 4);
  const unsigned short* src0;
  int kstr, wbOff;
  if (isK) {
    const int key = w * 16 + (lane >> 2);
    const int gseg = (lane & 3) ^ ((lane >> 3) & 3);  // seg ^ ((key>>1)&3)
    src0 = KH + ((size_t)bh * 4096 + key) * 32 + gseg * 8;
    kstr = 32;          // shorts per key step
    wbOff = w * 1024;   // K region
  } else {
    const int r = (w - 4) * 8 + (lane >> 3), useg = lane & 7;
    src0 = VT + ((size_t)bh * 32 + r) * 4096 + ((useg ^ (r & 7)) * 8);
    kstr = 1;
    wbOff = 4096 + (w - 4) * 1024;  // V region
  }

  async_cp16(src0, smem + wbOff);  // preload tile 0 -> buf 0
  __syncthreads();

  f32x4 acc[2][2];  // O_relu^T partials: col=q=l15, row=d=dt*16+quad*4+r
#pragma unroll
  for (int s = 0; s < 2; s++) {
    acc[s][0] = zero;
    acc[s][1] = zero;
  }

  const int rs = l15 & 7;
  const int kseg = (quad ^ ((l15 >> 1) & 3)) * 16;  // K-tile read de-swizzle
  for (int i = 0; i < 64; i++) {
    const int nb = i & 1;
    const int kn = ((i + 1) & 63) * 64;  // next key base (wraps, in-bounds)
    async_cp16(src0 + (size_t)kn * kstr, smem + (nb ^ 1) * 8192 + wbOff);

    const char* Kb = smem + nb * 8192;
    const char* Vb = Kb + 4096;
    short8 kf[4];
#pragma unroll
    for (int c = 0; c < 4; c++)
      kf[c] = *(const short8*)(Kb + (c * 16 + l15) * 64 + kseg);
    short8 vf[2][2];  // [dt][u]: V^T rows dt*16+l15, VT-order keys 32u+quad*8..+7
#pragma unroll
    for (int dt = 0; dt < 2; dt++) {
      const char* Vr = Vb + (dt * 16 + l15) * 128;
#pragma unroll
      for (int u = 0; u < 2; u++)
        vf[dt][u] = *(const short8*)(Vr + (((4 * u + quad) ^ rs) * 16));
    }

#pragma unroll
    for (int s = 0; s < 2; s++) {
      unsigned int pp[4][2];  // tile c: packed relu(S), keys 16c+quad*4+{0..3}
#pragma unroll
      for (int c = 0; c < 4; c++) {
        f32x4 st = MFMA16x32(kf[c], qf[s], zero);  // S^T 16key x 16q
        pp[c][0] = relu_pk_bf16(pack_bf16(st[0], st[1]));
        pp[c][1] = relu_pk_bf16(pack_bf16(st[2], st[3]));
      }
#pragma unroll
      for (int u = 0; u < 2; u++) {
        // B-frag slot k=quad*8+j holds phys key 32u+16*(j>>2)+4*quad+(j&3)
        // == VT-order key 32u+quad*8+j (by the VT permutation). No shuffles.
        u32x4 bw = {pp[2 * u][0], pp[2 * u][1],
                    pp[2 * u + 1][0], pp[2 * u + 1][1]};
        short8 pb = __builtin_bit_cast(short8, bw);
#pragma unroll
        for (int dt = 0; dt < 2; dt++)
          acc[s][dt] = MFMA16x32(vf[dt][u], pb, acc[s][dt]);
      }
    }
    __syncthreads();
  }

  // Epilogue: O = 0.8*O_relu + 0.2*(Qs*M). corr D[m=d,n=q] matches acc
  // layout (A=ma: m=l15=d_local, k=i; B=qf[s]: n=l15=q, k=i=quad*8+j).
#pragma unroll
  for (int s = 0; s < 2; s++)
#pragma unroll
    for (int dt = 0; dt < 2; dt++) {
      f32x4 corr = MFMA16x32(ma[dt], qf[s], zero);
      f32x4 o = acc[s][dt] * 0.8f + corr * 0.2f;
      *(f32x4*)(out + ((size_t)b * 4096 + qbase + s * 16 + l15) * 256 + h * 32 +
                dt * 16 + quad * 4) = o;
    }
}

// ---------------------------------------------------------------------------
extern "C" void kernel_launch(void* const* d_in, const int* in_sizes, int n_in,
                              void* d_out, int out_size, void* d_ws,
                              size_t ws_size, hipStream_t stream) {
  const float* x = (const float*)d_in[0];
  const float* Wq = (const float*)d_in[1];
  const float* Wk = (const float*)d_in[2];
  const float* Wv = (const float*)d_in[3];
  float* out = (float*)d_out;

  // Workspace: QH | KH | VT | xb | WT | MP(f32)   (~35 MB)
  unsigned short* ws = (unsigned short*)d_ws;
  unsigned short* QHb = ws;                // 32 bh * 4096 n * 32 d
  unsigned short* KHb = ws + 4194304;      // 32 bh * 4096 n * 32 d
  unsigned short* VTb = ws + 2 * 4194304;  // 32 bh * 32 d * 4096 n (permuted)
  unsigned short* xbb = ws + 3 * 4194304;  // 16384*256
  unsigned short* WTb = ws + 4 * 4194304;  // 3 * 256 * 256
  float* MPf = (float*)(WTb + 196608);     // 256 blk * 1024 f32 (1MB)

  prep_kernel<<<4288, 256, 0, stream>>>(x, xbb, Wq, Wk, Wv, WTb);
  proj_kernel<<<768, 256, 0, stream>>>(xbb, WTb, QHb, KHb, VTb);
  mkv_kernel<<<256, 512, 0, stream>>>(KHb, VTb, MPf);
  attn_kernel<<<512, 512, 0, stream>>>(QHb, KHb, VTb, MPf, out);
}

// Round 18
// 153.342 us; speedup vs baseline: 1.0962x; 1.0962x over previous
//
#include <hip/hip_runtime.h>

typedef __attribute__((ext_vector_type(8))) short short8;
typedef __attribute__((ext_vector_type(4))) float f32x4;
typedef __attribute__((ext_vector_type(2))) unsigned int u32x2;
typedef __attribute__((ext_vector_type(4))) unsigned int u32x4;

#define MFMA16x32(A, B, C) \
  __builtin_amdgcn_mfma_f32_16x16x32_bf16((A), (B), (C), 0, 0, 0)

// Async global->LDS, 16B/lane. Global addr is per-lane; LDS dest is the
// WAVE-UNIFORM base (HW scatters lane i -> base + i*16).
__device__ __forceinline__ void async_cp16(const unsigned short* g, void* l) {
  __builtin_amdgcn_global_load_lds(
      (const __attribute__((address_space(1))) unsigned int*)g,
      (__attribute__((address_space(3))) unsigned int*)l, 16, 0, 0);
}

__device__ __forceinline__ unsigned int fbits(float f) {
  return __builtin_bit_cast(unsigned int, f);
}
// pack two floats -> two bf16 (truncate): low ushort = a, high = b
__device__ __forceinline__ unsigned int pack_bf16(float a, float b) {
  return __builtin_amdgcn_perm(fbits(b), fbits(a), 0x07060302u);
}
__device__ __forceinline__ unsigned short bf16_rne(float f) {
  unsigned int u = fbits(f);
  return (unsigned short)((u + 0x8000u) >> 16);
}
// relu on a PACKED bf16 pair: bf16 bit patterns are sign-monotone as i16, so
// max_i16 with 0 zeroes the negative half-words. 1 instr for 2 elements.
__device__ __forceinline__ unsigned int relu_pk_bf16(unsigned int x) {
  unsigned int r;
  asm("v_pk_max_i16 %0, %1, 0" : "=v"(r) : "v"(x));
  return r;
}

// ---------------------------------------------------------------------------
// Kernel 0 (fused): blocks < 4096: x fp32 -> bf16.  blocks >= 4096: W -> WT
// (bf16, [n][k]) for all three weights.
// ---------------------------------------------------------------------------
__global__ __launch_bounds__(256) void prep_kernel(
    const float* __restrict__ x, unsigned short* __restrict__ xb,
    const float* __restrict__ Wq, const float* __restrict__ Wk,
    const float* __restrict__ Wv, unsigned short* __restrict__ WT) {
  __shared__ float tile[32][33];
  if (blockIdx.x < 4096) {
    const size_t i = ((size_t)blockIdx.x * 256 + threadIdx.x) * 4;
    const float4 f = *(const float4*)(x + i);
    u32x2 u = {(unsigned int)bf16_rne(f.x) | ((unsigned int)bf16_rne(f.y) << 16),
               (unsigned int)bf16_rne(f.z) | ((unsigned int)bf16_rne(f.w) << 16)};
    *(u32x2*)(xb + i) = u;
    return;
  }
  const int bid = blockIdx.x - 4096;
  const int g = bid / 64, rem = bid % 64;
  const int k0 = (rem >> 3) * 32, n0 = (rem & 7) * 32;
  const float* W = (g == 0) ? Wq : (g == 1) ? Wk : Wv;
  const int t = threadIdx.x;
  {
    const int kr = t >> 3, nc = (t & 7) * 4;
    const float4 f = *(const float4*)(W + (size_t)(k0 + kr) * 256 + n0 + nc);
    tile[kr][nc + 0] = f.x; tile[kr][nc + 1] = f.y;
    tile[kr][nc + 2] = f.z; tile[kr][nc + 3] = f.w;
  }
  __syncthreads();
  {
    const int nr = t >> 3, kc = (t & 7) * 4;
    unsigned int u0 = (unsigned int)bf16_rne(tile[kc + 0][nr]) |
                      ((unsigned int)bf16_rne(tile[kc + 1][nr]) << 16);
    unsigned int u1 = (unsigned int)bf16_rne(tile[kc + 2][nr]) |
                      ((unsigned int)bf16_rne(tile[kc + 3][nr]) << 16);
    u32x2 u = {u0, u1};
    *(u32x2*)(WT + (size_t)g * 65536 + (size_t)(n0 + nr) * 256 + k0 + kc) = u;
  }
}

// ---------------------------------------------------------------------------
// Kernel 1: fused QKV projection GEMM, LDS-staged, BK=64 dbuf. 128m x 128n
// tile, 4 waves. Q/K written packed per head: QH/KH[bh][n][32] (Q pre-scaled
// by 1/sqrt(dk)); V written transposed VT[bh*32+d][n] with a key-order
// permutation inside each 32-n group: phys n = s*16+quad*4+r stored at
// n' = (n&~31)|(quad<<3)|(s<<2)|r, so attn's packed S^T registers ARE the
// K=32 MFMA B-fragment (reduction over keys is order-invariant as long as
// P and V use the same key order).
// ---------------------------------------------------------------------------
__global__ __launch_bounds__(256, 2) void proj_kernel(
    const unsigned short* __restrict__ xb, const unsigned short* __restrict__ WT,
    unsigned short* __restrict__ QH, unsigned short* __restrict__ KH,
    unsigned short* __restrict__ VT) {
  __shared__ __align__(16) char smem[65536];  // dbuf x (A 16K + B 16K)
  const int tid = threadIdx.x;
  const int w = tid >> 6, lane = tid & 63, l15 = lane & 15, quad = lane >> 4;
  const int bid = blockIdx.x;
  const int mtile = bid / 6, nt = bid % 6;
  const int g = nt >> 1, n0 = (nt & 1) * 128;
  const int m0 = mtile * 128;

  // Staging: wave w covers tile-rows w*32..+32 (4 instrs of 8 rows each).
  // LDS row r holds global 16B-seg (u ^ (r&7)) at seg u (XOR swizzle).
  const int srow = lane >> 3, useg = lane & 7;
  const int swz = (useg ^ srow) * 8;  // shorts
  const unsigned short* aS = xb + (size_t)(m0 + w * 32 + srow) * 256 + swz;
  const unsigned short* bS =
      WT + (size_t)g * 65536 + (size_t)(n0 + w * 32 + srow) * 256 + swz;

#pragma unroll
  for (int j = 0; j < 4; j++) {  // preload k-tile 0 -> buf 0
    async_cp16(aS + j * 2048, smem + w * 4096 + j * 1024);
    async_cp16(bS + j * 2048, smem + 16384 + w * 4096 + j * 1024);
  }
  __syncthreads();

  const f32x4 zero = {0.f, 0.f, 0.f, 0.f};
  f32x4 acc[2][8];
#pragma unroll
  for (int s = 0; s < 2; s++)
#pragma unroll
    for (int c = 0; c < 8; c++) acc[s][c] = zero;

  const int sw = l15 & 7;
  for (int t = 0; t < 4; t++) {
    const int nb = t & 1;
    const int kn = ((t + 1) & 3) * 64;  // wraps; last prefetch harmless
#pragma unroll
    for (int j = 0; j < 4; j++) {
      async_cp16(aS + kn + j * 2048,
                 smem + (nb ^ 1) * 32768 + w * 4096 + j * 1024);
      async_cp16(bS + kn + j * 2048,
                 smem + (nb ^ 1) * 32768 + 16384 + w * 4096 + j * 1024);
    }
    const char* Ab = smem + nb * 32768;
    const char* Bb = Ab + 16384;
#pragma unroll
    for (int ks = 0; ks < 2; ks++) {
      const int seg = ((ks * 4 + quad) ^ sw) * 16;
      short8 af[2], bf[8];
#pragma unroll
      for (int s = 0; s < 2; s++)
        af[s] = *(const short8*)(Ab + (w * 32 + s * 16 + l15) * 128 + seg);
#pragma unroll
      for (int c = 0; c < 8; c++)
        bf[c] = *(const short8*)(Bb + (c * 16 + l15) * 128 + seg);
      if (g < 2) {
#pragma unroll
        for (int s = 0; s < 2; s++)
#pragma unroll
          for (int c = 0; c < 8; c++)
            acc[s][c] = MFMA16x32(bf[c], af[s], acc[s][c]);  // swapped
      } else {
#pragma unroll
        for (int s = 0; s < 2; s++)
#pragma unroll
          for (int c = 0; c < 8; c++)
            acc[s][c] = MFMA16x32(af[s], bf[c], acc[s][c]);
      }
    }
    __syncthreads();
  }

  if (g < 2) {
    // Swapped orientation: rows m0+w*32+s*16+l15 (seq), cols n0+c*16+quad*4
    // (+reg) = feature -> packed 8B stores into [bh][n][32].
    unsigned short* O = g ? KH : QH;
    const float sc = g ? 1.0f : 0.17677669529663688f;  // 1/sqrt(32) into Q
#pragma unroll
    for (int s = 0; s < 2; s++)
#pragma unroll
      for (int c = 0; c < 8; c++) {
        const int row = m0 + w * 32 + s * 16 + l15;
        const int col = n0 + c * 16 + quad * 4;
        const int bb = row >> 12, nn = row & 4095;
        const int hh = col >> 5, dl = col & 31;
        u32x2 pk = {pack_bf16(acc[s][c][0] * sc, acc[s][c][1] * sc),
                    pack_bf16(acc[s][c][2] * sc, acc[s][c][3] * sc)};
        *(u32x2*)(O + ((size_t)(bb * 8 + hh) * 4096 + nn) * 32 + dl) = pk;
      }
  } else {
    // Natural orientation: reg-dim = 4 consecutive n -> contiguous in VT.
    // Key-permutation: phys n low5 = s*16+quad*4+r stored at quad*8+s*4+r.
#pragma unroll
    for (int s = 0; s < 2; s++)
#pragma unroll
      for (int c = 0; c < 8; c++) {
        const int col = n0 + c * 16 + l15;  // h*32 + d
        const int hh = col >> 5, dl = col & 31;
        const int row = m0 + w * 32 + s * 16 + quad * 4;
        const int bb = row >> 12;
        const int nn = (row & 4064) | (quad << 3) | ((s & 1) << 2);  // &~31
        u32x2 pk = {pack_bf16(acc[s][c][0], acc[s][c][1]),
                    pack_bf16(acc[s][c][2], acc[s][c][3])};
        *(u32x2*)(VT + (size_t)((bb * 8 + hh) * 32 + dl) * 4096 + nn) = pk;
      }
  }
}

// ---------------------------------------------------------------------------
// Kernel 1.5a: partial M = K^T V. Grid 256 = 32 bh x 8 key-slices (vs R16's
// 32-block version: 8x CU coverage, 32 gather loads/lane instead of 256).
// Per block: wave w covers keys slice*512 + w*64 (+2 groups of 32). A = V^T
// frag (16B contiguous from VT, keys in VT order); B = K frag by register
// element-inserts with constant indices (no scratch). VT-pos p=quad*8+j
// decodes to key kb+(j>>2)*16+quad*4+(j&3) — same key pairing for A and B
// -> order-invariant sum. LDS reduce across 8 waves; wave 0 writes the f32
// partial in attn's per-lane A-frag order: MP[blk*1024 + dt*512 + lane*8].
// ---------------------------------------------------------------------------
__global__ __launch_bounds__(512) void mkv_kernel(
    const unsigned short* __restrict__ KH, const unsigned short* __restrict__ VT,
    float* __restrict__ MP) {
  __shared__ __align__(16) float Mred[8][32][32];  // 32KB
  const int tid = threadIdx.x;
  const int w = tid >> 6, lane = tid & 63, l15 = lane & 15, quad = lane >> 4;
  const int blk = blockIdx.x;
  const int bh = blk >> 3, slice = blk & 7;

  const f32x4 zero = {0.f, 0.f, 0.f, 0.f};
  f32x4 mm[2][2];
#pragma unroll
  for (int dt = 0; dt < 2; dt++)
#pragma unroll
    for (int it = 0; it < 2; it++) mm[dt][it] = zero;

  const unsigned short* Vg = VT + ((size_t)bh * 32 + l15) * 4096 + quad * 8;
  const unsigned short* Kg = KH + (size_t)bh * 4096 * 32;

#pragma unroll
  for (int g = 0; g < 2; g++) {
    const int kb = slice * 512 + w * 64 + g * 32;
    short8 va[2];
#pragma unroll
    for (int dt = 0; dt < 2; dt++)
      va[dt] = *(const short8*)(Vg + (size_t)dt * 16 * 4096 + kb);
    short8 kv0, kv1;
#pragma unroll
    for (int j = 0; j < 8; j++) {  // VT-pos p=quad*8+j -> natural key n(p)
      const int key = kb + ((j >> 2) << 4) + quad * 4 + (j & 3);
      const size_t base = (size_t)key * 32 + l15;
      kv0[j] = (short)Kg[base];
      kv1[j] = (short)Kg[base + 16];
    }
#pragma unroll
    for (int dt = 0; dt < 2; dt++) {
      mm[dt][0] = MFMA16x32(va[dt], kv0, mm[dt][0]);
      mm[dt][1] = MFMA16x32(va[dt], kv1, mm[dt][1]);
    }
  }
  // D layout: row d_local = quad*4+r (+dt*16), col i_local = l15 (+it*16).
#pragma unroll
  for (int dt = 0; dt < 2; dt++)
#pragma unroll
    for (int it = 0; it < 2; it++)
#pragma unroll
      for (int r = 0; r < 4; r++)
        Mred[w][dt * 16 + quad * 4 + r][it * 16 + l15] = mm[dt][it][r];
  __syncthreads();

  if (w == 0) {
#pragma unroll
    for (int dt = 0; dt < 2; dt++) {
      f32x4 sa = zero, sb = zero;
#pragma unroll
      for (int ww = 0; ww < 8; ww++) {
        const float* p = &Mred[ww][dt * 16 + l15][quad * 8];
        sa += *(const f32x4*)p;
        sb += *(const f32x4*)(p + 4);
      }
      float* o = MP + (size_t)blk * 1024 + dt * 512 + lane * 8;
      *(f32x4*)o = sa;
      *(f32x4*)(o + 4) = sb;
    }
  }
}

// ---------------------------------------------------------------------------
// Kernel 1.5b: reduce the 8 f32 partial slices -> bf16 MW in attn's A-frag
// layout. 8 blocks x 256 threads = 2048 lanes = 32 bh x 64 lane; ~512B of
// L2-hit loads each. Kept OUT of attn: R17 proved in-attn reduction spills
// (attn's main loop has zero register headroom — VGPR 48->64, 100MB scratch).
// ---------------------------------------------------------------------------
__global__ __launch_bounds__(256) void mred_kernel(
    const float* __restrict__ MP, unsigned short* __restrict__ MW) {
  const int tid = threadIdx.x;
  const int bh = blockIdx.x * 4 + (tid >> 6), lane = tid & 63;
  const f32x4 zero = {0.f, 0.f, 0.f, 0.f};
#pragma unroll
  for (int dt = 0; dt < 2; dt++) {
    f32x4 sa = zero, sb = zero;
#pragma unroll
    for (int sl = 0; sl < 8; sl++) {
      const float* p =
          MP + (size_t)(bh * 8 + sl) * 1024 + dt * 512 + lane * 8;
      sa += *(const f32x4*)p;
      sb += *(const f32x4*)(p + 4);
    }
    u32x4 mw = {pack_bf16(sa[0], sa[1]), pack_bf16(sa[2], sa[3]),
                pack_bf16(sb[0], sb[1]), pack_bf16(sb[2], sb[3])};
    *(u32x4*)(MW + (size_t)bh * 1024 + dt * 512 + lane * 8) = mw;
  }
}

// ---------------------------------------------------------------------------
// Kernel 2: attention — byte-identical to the R16-verified kernel (attn
// 63.8us, VGPR 48, MfmaUtil 45, FETCH 12.3MB): R4 structure + leaky
// decomposition leaky(x) = 0.8*relu(x) + 0.2*x  =>  O = 0.8 * V^T relu(S)
// + 0.2 * Qs*M, with M = K^T V read as TWO 16B bf16 loads from MW (R17
// proved anything heavier in the prologue spills the main loop).
// Main-loop leaky: pack + v_pk_max_i16 (4 instrs/tile). Epilogue: out =
// 0.8*acc + 0.2*mfma(ma[dt], qf[s]) — ma is the A-frag [d=l15][i=quad*8+j],
// qf doubles as the B-frag [k=i][n=q=l15].
// Dead ends (do not revisit): split-K (101), counted-vmcnt (97), 2-tile
// epochs (92), q_w=16 (110), q_w=64 (97), 4-wave domains (101), setprio
// (104), LDS-free (191), leaky_pack f32x2 helper (98), in-attn M compute
// (104), in-attn M f32-reduce (85), 32-block mkv (13us).
// ---------------------------------------------------------------------------
__global__ __launch_bounds__(512, 4) void attn_kernel(
    const unsigned short* __restrict__ QH, const unsigned short* __restrict__ KH,
    const unsigned short* __restrict__ VT, const unsigned short* __restrict__ MW,
    float* __restrict__ out) {
  __shared__ __align__(16) char smem[16384];  // dbuf x (K 4K + V 4K)
  const int tid = threadIdx.x;
  const int w = tid >> 6, lane = tid & 63, l15 = lane & 15, quad = lane >> 4;
  const int bid = blockIdx.x;
  const int bh = bid & 31, qh = bid >> 5;  // bid%8 = bh%8: KV L2-local per XCD
  const int b = bh >> 3, h = bh & 7;
  const int qbase = qh * 256 + w * 32;

  // Q frags once (packed head layout -> contiguous loads).
  const unsigned short* Qp =
      QH + ((size_t)bh * 4096 + qbase + l15) * 32 + quad * 8;
  short8 qf[2];
#pragma unroll
  for (int s = 0; s < 2; s++) qf[s] = *(const short8*)(Qp + (size_t)s * 512);

  // M frags (pre-packed per-lane by mred_kernel): 2x 16B loads.
  short8 ma[2];
#pragma unroll
  for (int dt = 0; dt < 2; dt++)
    ma[dt] = *(const short8*)(MW + (size_t)bh * 1024 + dt * 512 + lane * 8);

  // Staging setup (per lane global src; wave-uniform LDS base).
  const bool isK = (w < 4);
  const unsigned short* src0;
  int kstr, wbOff;
  if (isK) {
    const int key = w * 16 + (lane >> 2);
    const int gseg = (lane & 3) ^ ((lane >> 3) & 3);  // seg ^ ((key>>1)&3)
    src0 = KH + ((size_t)bh * 4096 + key) * 32 + gseg * 8;
    kstr = 32;          // shorts per key step
    wbOff = w * 1024;   // K region
  } else {
    const int r = (w - 4) * 8 + (lane >> 3), useg = lane & 7;
    src0 = VT + ((size_t)bh * 32 + r) * 4096 + ((useg ^ (r & 7)) * 8);
    kstr = 1;
    wbOff = 4096 + (w - 4) * 1024;  // V region
  }

  async_cp16(src0, smem + wbOff);  // preload tile 0 -> buf 0
  __syncthreads();

  const f32x4 zero = {0.f, 0.f, 0.f, 0.f};
  f32x4 acc[2][2];  // O_relu^T partials: col=q=l15, row=d=dt*16+quad*4+r
#pragma unroll
  for (int s = 0; s < 2; s++) {
    acc[s][0] = zero;
    acc[s][1] = zero;
  }

  const int rs = l15 & 7;
  const int kseg = (quad ^ ((l15 >> 1) & 3)) * 16;  // K-tile read de-swizzle
  for (int i = 0; i < 64; i++) {
    const int nb = i & 1;
    const int kn = ((i + 1) & 63) * 64;  // next key base (wraps, in-bounds)
    async_cp16(src0 + (size_t)kn * kstr, smem + (nb ^ 1) * 8192 + wbOff);

    const char* Kb = smem + nb * 8192;
    const char* Vb = Kb + 4096;
    short8 kf[4];
#pragma unroll
    for (int c = 0; c < 4; c++)
      kf[c] = *(const short8*)(Kb + (c * 16 + l15) * 64 + kseg);
    short8 vf[2][2];  // [dt][u]: V^T rows dt*16+l15, VT-order keys 32u+quad*8..+7
#pragma unroll
    for (int dt = 0; dt < 2; dt++) {
      const char* Vr = Vb + (dt * 16 + l15) * 128;
#pragma unroll
      for (int u = 0; u < 2; u++)
        vf[dt][u] = *(const short8*)(Vr + (((4 * u + quad) ^ rs) * 16));
    }

#pragma unroll
    for (int s = 0; s < 2; s++) {
      unsigned int pp[4][2];  // tile c: packed relu(S), keys 16c+quad*4+{0..3}
#pragma unroll
      for (int c = 0; c < 4; c++) {
        f32x4 st = MFMA16x32(kf[c], qf[s], zero);  // S^T 16key x 16q
        pp[c][0] = relu_pk_bf16(pack_bf16(st[0], st[1]));
        pp[c][1] = relu_pk_bf16(pack_bf16(st[2], st[3]));
      }
#pragma unroll
      for (int u = 0; u < 2; u++) {
        // B-frag slot k=quad*8+j holds phys key 32u+16*(j>>2)+4*quad+(j&3)
        // == VT-order key 32u+quad*8+j (by the VT permutation). No shuffles.
        u32x4 bw = {pp[2 * u][0], pp[2 * u][1],
                    pp[2 * u + 1][0], pp[2 * u + 1][1]};
        short8 pb = __builtin_bit_cast(short8, bw);
#pragma unroll
        for (int dt = 0; dt < 2; dt++)
          acc[s][dt] = MFMA16x32(vf[dt][u], pb, acc[s][dt]);
      }
    }
    __syncthreads();
  }

  // Epilogue: O = 0.8*O_relu + 0.2*(Qs*M). corr D[m=d,n=q] matches acc
  // layout (A=ma: m=l15=d_local, k=i; B=qf[s]: n=l15=q, k=i=quad*8+j).
#pragma unroll
  for (int s = 0; s < 2; s++)
#pragma unroll
    for (int dt = 0; dt < 2; dt++) {
      f32x4 corr = MFMA16x32(ma[dt], qf[s], zero);
      f32x4 o = acc[s][dt] * 0.8f + corr * 0.2f;
      *(f32x4*)(out + ((size_t)b * 4096 + qbase + s * 16 + l15) * 256 + h * 32 +
                dt * 16 + quad * 4) = o;
    }
}

// ---------------------------------------------------------------------------
extern "C" void kernel_launch(void* const* d_in, const int* in_sizes, int n_in,
                              void* d_out, int out_size, void* d_ws,
                              size_t ws_size, hipStream_t stream) {
  const float* x = (const float*)d_in[0];
  const float* Wq = (const float*)d_in[1];
  const float* Wk = (const float*)d_in[2];
  const float* Wv = (const float*)d_in[3];
  float* out = (float*)d_out;

  // Workspace: QH | KH | VT | xb | WT | MP(f32) | MW(bf16)   (~35 MB)
  unsigned short* ws = (unsigned short*)d_ws;
  unsigned short* QHb = ws;                // 32 bh * 4096 n * 32 d
  unsigned short* KHb = ws + 4194304;      // 32 bh * 4096 n * 32 d
  unsigned short* VTb = ws + 2 * 4194304;  // 32 bh * 32 d * 4096 n (permuted)
  unsigned short* xbb = ws + 3 * 4194304;  // 16384*256
  unsigned short* WTb = ws + 4 * 4194304;  // 3 * 256 * 256
  float* MPf = (float*)(WTb + 196608);     // 256 blk * 1024 f32 (1MB)
  unsigned short* MWb = (unsigned short*)(MPf + 262144);  // 32 bh * 1024

  prep_kernel<<<4288, 256, 0, stream>>>(x, xbb, Wq, Wk, Wv, WTb);
  proj_kernel<<<768, 256, 0, stream>>>(xbb, WTb, QHb, KHb, VTb);
  mkv_kernel<<<256, 512, 0, stream>>>(KHb, VTb, MPf);
  mred_kernel<<<8, 256, 0, stream>>>(MPf, MWb);
  attn_kernel<<<512, 512, 0, stream>>>(QHb, KHb, VTb, MWb, out);
}